// Round 1
// baseline (767.361 us; speedup 1.0000x reference)
//
#include <hip/hip_runtime.h>

typedef short short8 __attribute__((ext_vector_type(8)));
typedef float floatx4 __attribute__((ext_vector_type(4)));

#define BM 128
#define BN 128
#define BK 32

// Async global->LDS, 16B per lane. LDS dest must be wave-uniform base; HW
// writes base + lane*16 (cdna_hip_programming.md §5 caveat).
__device__ __forceinline__ void async_copy16(const void* g, void* l) {
  __builtin_amdgcn_global_load_lds((const __attribute__((address_space(1))) void*)g,
                                   (__attribute__((address_space(3))) void*)l, 16, 0, 0);
}

__global__ __launch_bounds__(256) void absmax_kernel(const float* __restrict__ x,
                                                     size_t n4,
                                                     unsigned* __restrict__ out) {
  size_t i = (size_t)blockIdx.x * blockDim.x + threadIdx.x;
  size_t stride = (size_t)gridDim.x * blockDim.x;
  const float4* x4 = (const float4*)x;
  float m = 0.0f;
  for (; i < n4; i += stride) {
    float4 v = x4[i];
    m = fmaxf(m, fmaxf(fmaxf(fabsf(v.x), fabsf(v.y)), fmaxf(fabsf(v.z), fabsf(v.w))));
  }
#pragma unroll
  for (int off = 32; off > 0; off >>= 1)
    m = fmaxf(m, __shfl_down(m, off, 64));
  __shared__ float red[4];
  int wave = threadIdx.x >> 6, lane = threadIdx.x & 63;
  if (lane == 0) red[wave] = m;
  __syncthreads();
  if (threadIdx.x == 0) {
    m = fmaxf(fmaxf(red[0], red[1]), fmaxf(red[2], red[3]));
    // non-negative floats: uint bit order == float order
    atomicMax(out, __float_as_uint(m));
  }
}

// q = clip(rint(v/s), qmin, qmax), stored as bf16 (exact: |q| <= 128)
__global__ __launch_bounds__(256) void quant_kernel(const float* __restrict__ x,
                                                    unsigned short* __restrict__ q,
                                                    size_t n,
                                                    const unsigned* __restrict__ amax,
                                                    float qmin, float qmax) {
  float s = __uint_as_float(*amax) / 127.0f;  // same op as reference
  size_t i = ((size_t)blockIdx.x * blockDim.x + threadIdx.x) * 8;
  size_t stride = (size_t)gridDim.x * blockDim.x * 8;
  for (; i < n; i += stride) {
    float4 v0 = *(const float4*)(x + i);
    float4 v1 = *(const float4*)(x + i + 4);
    float f[8] = {v0.x, v0.y, v0.z, v0.w, v1.x, v1.y, v1.z, v1.w};
    uint4 u;
    unsigned p[4];
#pragma unroll
    for (int j = 0; j < 4; ++j) {
      float a = fminf(fmaxf(rintf(f[2 * j] / s), qmin), qmax);
      float b = fminf(fmaxf(rintf(f[2 * j + 1] / s), qmin), qmax);
      // integer-valued -> truncation to bf16 is exact
      p[j] = (__float_as_uint(a) >> 16) | (__float_as_uint(b) & 0xffff0000u);
    }
    u.x = p[0]; u.y = p[1]; u.z = p[2]; u.w = p[3];
    *(uint4*)(q + i) = u;
  }
}

// C[m,n] = sum_k qx[m,k]*qw[n,k]; out = 4*sx*sw*C + 4*b[n]
// m97 structure: 128x128 tile, BK=32, 4 waves in 2x2, each 4x4 of 16x16x32 MFMA.
__global__ __launch_bounds__(256) void gemm_kernel(
    const short* __restrict__ qx, const short* __restrict__ qw,
    const float* __restrict__ bias, const unsigned* __restrict__ amax,
    float* __restrict__ out, int M, int N, int K) {
  __shared__ __align__(16) short As[BM * BK];  // 8 KB, row-major [m][k]
  __shared__ __align__(16) short Bs[BN * BK];  // 8 KB, row-major [n][k]
  int tid = threadIdx.x;
  int wave = tid >> 6, lane = tid & 63;
  int wm = (wave >> 1) * 64, wn = (wave & 1) * 64;
  int bm = blockIdx.y * BM, bn = blockIdx.x * BN;

  // staging: tile = 8 chunks of 1024B; wave w stages chunks {2w, 2w+1}.
  // chunk c: lane l -> row c*16 + l/4, col (l&3)*8 (16B)
  int lrow = lane >> 2;
  int lcol = (lane & 3) * 8;
  const short* gA = qx + ((size_t)bm + lrow) * K + lcol;
  const short* gB = qw + ((size_t)bn + lrow) * K + lcol;
  int c0 = wave * 2;

  floatx4 acc[4][4] = {};

  int r = lane & 15;
  int kq = (lane >> 4) * 8;

  for (int kt = 0; kt < K; kt += BK) {
#pragma unroll
    for (int c = 0; c < 2; ++c) {
      int cc = c0 + c;
      async_copy16(gA + (size_t)(cc * 16) * K + kt, As + cc * 512);
      async_copy16(gB + (size_t)(cc * 16) * K + kt, Bs + cc * 512);
    }
    __syncthreads();  // compiler drains vmcnt before barrier
    short8 a[4], b[4];
#pragma unroll
    for (int i = 0; i < 4; ++i)
      a[i] = *(const short8*)(As + (wm + i * 16 + r) * BK + kq);
#pragma unroll
    for (int j = 0; j < 4; ++j)
      b[j] = *(const short8*)(Bs + (wn + j * 16 + r) * BK + kq);
#pragma unroll
    for (int i = 0; i < 4; ++i)
#pragma unroll
      for (int j = 0; j < 4; ++j)
        acc[i][j] = __builtin_amdgcn_mfma_f32_16x16x32_bf16(a[i], b[j], acc[i][j], 0, 0, 0);
    __syncthreads();  // protect LDS before next stage
  }

  float sx = __uint_as_float(amax[0]) / 127.0f;
  float sw = __uint_as_float(amax[1]) / 127.0f;
  float scale = 4.0f * sx * sw;
  // C/D layout (m89/m91 verified): col = lane&15, row = (lane>>4)*4 + reg
  int col = lane & 15;
  int rq = (lane >> 4) * 4;
#pragma unroll
  for (int j = 0; j < 4; ++j) {
    int gn = bn + wn + j * 16 + col;
    float b4 = 4.0f * bias[gn];
#pragma unroll
    for (int i = 0; i < 4; ++i) {
      size_t base = (size_t)(bm + wm + i * 16 + rq) * N + gn;
#pragma unroll
      for (int rr = 0; rr < 4; ++rr)
        out[base + (size_t)rr * N] = scale * acc[i][j][rr] + b4;
    }
  }
}

extern "C" void kernel_launch(void* const* d_in, const int* in_sizes, int n_in,
                              void* d_out, int out_size, void* d_ws, size_t ws_size,
                              hipStream_t stream) {
  const float* x = (const float*)d_in[0];
  const float* W = (const float*)d_in[1];
  const float* b = (const float*)d_in[2];
  float* out = (float*)d_out;

  int Nv = in_sizes[2];            // 4096 (OUT)
  int K = in_sizes[1] / Nv;        // 4096 (IN)
  int M = in_sizes[0] / K;         // 8192 (N rows)

  unsigned* amax = (unsigned*)d_ws;               // [0]=max|x| bits, [1]=max|W| bits
  short* qx = (short*)((char*)d_ws + 256);        // M*K bf16
  short* qw = qx + (size_t)M * K;                 // Nv*K bf16

  hipMemsetAsync(d_ws, 0, 8, stream);  // zero amax slots (ws is re-poisoned each call)
  absmax_kernel<<<1024, 256, 0, stream>>>(x, (size_t)M * K / 4, amax + 0);
  absmax_kernel<<<512, 256, 0, stream>>>(W, (size_t)Nv * K / 4, amax + 1);
  quant_kernel<<<4096, 256, 0, stream>>>(x, (unsigned short*)qx, (size_t)M * K,
                                         amax + 0, -128.0f, 127.0f);
  quant_kernel<<<2048, 256, 0, stream>>>(W, (unsigned short*)qw, (size_t)Nv * K,
                                         amax + 1, -127.0f, 127.0f);
  dim3 grid(Nv / BN, M / BM);
  gemm_kernel<<<grid, 256, 0, stream>>>(qx, qw, b, amax, out, M, Nv, K);
}

// Round 2
// 489.531 us; speedup vs baseline: 1.5675x; 1.5675x over previous
//
#include <hip/hip_runtime.h>

typedef int int4v __attribute__((ext_vector_type(4)));

#define BM 128
#define BN 128
#define BK 64  // 64 int8 along K per stage = 64 B/row

// Async global->LDS, 16B per lane; HW writes wave-uniform base + lane*16.
__device__ __forceinline__ void async_copy16(const void* g, void* l) {
  __builtin_amdgcn_global_load_lds((const __attribute__((address_space(1))) void*)g,
                                   (__attribute__((address_space(3))) void*)l, 16, 0, 0);
}

// One dispatch: blocks [0,xb) reduce x (n4x float4s), rest reduce w.
__global__ __launch_bounds__(256) void absmax2_kernel(
    const float* __restrict__ x, size_t n4x,
    const float* __restrict__ w, size_t n4w,
    unsigned* __restrict__ out, int xb) {
  const float4* src;
  size_t n4;
  unsigned* dst;
  int bid, nb;
  if ((int)blockIdx.x < xb) {
    src = (const float4*)x; n4 = n4x; dst = out; bid = blockIdx.x; nb = xb;
  } else {
    src = (const float4*)w; n4 = n4w; dst = out + 1; bid = blockIdx.x - xb; nb = gridDim.x - xb;
  }
  size_t i = (size_t)bid * blockDim.x + threadIdx.x;
  size_t stride = (size_t)nb * blockDim.x;
  float m = 0.0f;
  for (; i < n4; i += stride) {
    float4 v = src[i];
    m = fmaxf(m, fmaxf(fmaxf(fabsf(v.x), fabsf(v.y)), fmaxf(fabsf(v.z), fabsf(v.w))));
  }
#pragma unroll
  for (int off = 32; off > 0; off >>= 1)
    m = fmaxf(m, __shfl_down(m, off, 64));
  __shared__ float red[4];
  int wave = threadIdx.x >> 6, lane = threadIdx.x & 63;
  if (lane == 0) red[wave] = m;
  __syncthreads();
  if (threadIdx.x == 0) {
    m = fmaxf(fmaxf(red[0], red[1]), fmaxf(red[2], red[3]));
    atomicMax(dst, __float_as_uint(m));  // non-negative: uint order == float order
  }
}

// One dispatch: quantize x -> qx (int8, [-128,127]) and w -> qw ([-127,127]).
__global__ __launch_bounds__(256) void quant2_kernel(
    const float* __restrict__ x, char* __restrict__ qx, size_t nx,
    const float* __restrict__ w, char* __restrict__ qw, size_t nw,
    const unsigned* __restrict__ amax, int xb) {
  const float* src;
  char* dst;
  size_t n;
  float r, lo;
  int bid, nb;
  if ((int)blockIdx.x < xb) {
    src = x; dst = qx; n = nx; r = 127.0f / __uint_as_float(amax[0]);
    lo = -128.0f; bid = blockIdx.x; nb = xb;
  } else {
    src = w; dst = qw; n = nw; r = 127.0f / __uint_as_float(amax[1]);
    lo = -127.0f; bid = blockIdx.x - xb; nb = gridDim.x - xb;
  }
  size_t i = ((size_t)bid * blockDim.x + threadIdx.x) * 8;
  size_t stride = (size_t)nb * blockDim.x * 8;
  for (; i < n; i += stride) {
    float4 v0 = *(const float4*)(src + i);
    float4 v1 = *(const float4*)(src + i + 4);
    float f[8] = {v0.x, v0.y, v0.z, v0.w, v1.x, v1.y, v1.z, v1.w};
    unsigned w0 = 0, w1 = 0;
#pragma unroll
    for (int j = 0; j < 4; ++j) {
      int q0 = (int)fminf(fmaxf(rintf(f[j] * r), lo), 127.0f);
      int q1 = (int)fminf(fmaxf(rintf(f[4 + j] * r), lo), 127.0f);
      w0 |= (unsigned)(q0 & 0xff) << (8 * j);
      w1 |= (unsigned)(q1 & 0xff) << (8 * j);
    }
    uint2 u; u.x = w0; u.y = w1;
    *(uint2*)(dst + i) = u;
  }
}

// C[m,n] = sum_k qx[m,k]*qw[n,k] (exact i32); out = 4*sx*sw*C + 4*b[n].
// 128x128 tile, BK=64, 4 waves 2x2, each 4x4 of mfma_i32_16x16x64_i8.
__global__ __launch_bounds__(256) void gemm_i8_kernel(
    const char* __restrict__ qx, const char* __restrict__ qw,
    const float* __restrict__ bias, const unsigned* __restrict__ amax,
    float* __restrict__ out, int M, int N, int K) {
  __shared__ __align__(16) char As[BM * BK];  // 8 KB, row-major [m][64B]
  __shared__ __align__(16) char Bs[BN * BK];  // 8 KB
  int tid = threadIdx.x;
  int wave = tid >> 6, lane = tid & 63;
  int wm = (wave >> 1) * 64, wn = (wave & 1) * 64;

  // XCD-aware chimney swizzle: XCD p%8 gets a contiguous tile range,
  // M-tile fastest -> its B column band (1 MB) stays hot in that XCD's L2.
  int tilesM = M / BM, tilesN = N / BN;
  int T = tilesM * tilesN;
  int p = blockIdx.x;
  int tile;
  if ((T & 7) == 0) tile = (p & 7) * (T >> 3) + (p >> 3);
  else tile = p;
  int bm = (tile % tilesM) * BM;
  int bn = (tile / tilesM) * BN;

  // staging: each matrix tile = 8 chunks of 1024B (16 rows x 64B);
  // wave w stages chunks {2w,2w+1} of A and B. lane l -> row l/4, byte (l&3)*16.
  int lrow = lane >> 2;
  int lcol = (lane & 3) * 16;
  const char* gA = qx + ((size_t)bm + lrow) * K + lcol;
  const char* gB = qw + ((size_t)bn + lrow) * K + lcol;
  int c0 = wave * 2;

  int4v acc[4][4] = {};

  int r = lane & 15;
  int kb = (lane >> 4) * 16;  // byte offset of this lane's 16-elem K-fragment

  for (int kt = 0; kt < K; kt += BK) {
#pragma unroll
    for (int c = 0; c < 2; ++c) {
      int cc = c0 + c;
      async_copy16(gA + (size_t)(cc * 16) * K + kt, As + cc * 1024);
      async_copy16(gB + (size_t)(cc * 16) * K + kt, Bs + cc * 1024);
    }
    __syncthreads();
    int4v a[4], b[4];
#pragma unroll
    for (int i = 0; i < 4; ++i)
      a[i] = *(const int4v*)(As + (size_t)(wm + i * 16 + r) * BK + kb);
#pragma unroll
    for (int j = 0; j < 4; ++j)
      b[j] = *(const int4v*)(Bs + (size_t)(wn + j * 16 + r) * BK + kb);
#pragma unroll
    for (int i = 0; i < 4; ++i)
#pragma unroll
      for (int j = 0; j < 4; ++j)
        acc[i][j] = __builtin_amdgcn_mfma_i32_16x16x64_i8(a[i], b[j], acc[i][j], 0, 0, 0);
    __syncthreads();
  }

  float sx = __uint_as_float(amax[0]) / 127.0f;
  float sw = __uint_as_float(amax[1]) / 127.0f;
  float scale = 4.0f * sx * sw;
  // C/D layout (16x16 shapes, dtype-independent): col=lane&15, row=(lane>>4)*4+reg
  int col = lane & 15;
  int rq = (lane >> 4) * 4;
#pragma unroll
  for (int j = 0; j < 4; ++j) {
    int gn = bn + wn + j * 16 + col;
    float b4 = 4.0f * bias[gn];
#pragma unroll
    for (int i = 0; i < 4; ++i) {
      size_t base = (size_t)(bm + wm + i * 16 + rq) * N + gn;
#pragma unroll
      for (int rr = 0; rr < 4; ++rr)
        __builtin_nontemporal_store(scale * (float)acc[i][j][rr] + b4,
                                    out + base + (size_t)rr * N);
    }
  }
}

extern "C" void kernel_launch(void* const* d_in, const int* in_sizes, int n_in,
                              void* d_out, int out_size, void* d_ws, size_t ws_size,
                              hipStream_t stream) {
  const float* x = (const float*)d_in[0];
  const float* W = (const float*)d_in[1];
  const float* b = (const float*)d_in[2];
  float* out = (float*)d_out;

  int Nv = in_sizes[2];          // OUT = 4096
  int K = in_sizes[1] / Nv;      // IN  = 4096
  int M = in_sizes[0] / K;       // N rows = 8192

  size_t nx = (size_t)M * K, nw = (size_t)Nv * K;
  unsigned* amax = (unsigned*)d_ws;        // [0]=max|x| bits, [1]=max|W| bits
  char* qx = (char*)d_ws + 256;            // M*K int8
  char* qw = qx + nx;                      // Nv*K int8

  hipMemsetAsync(d_ws, 0, 8, stream);
  absmax2_kernel<<<1536, 256, 0, stream>>>(x, nx / 4, W, nw / 4, amax, 1024);
  quant2_kernel<<<3072, 256, 0, stream>>>(x, qx, nx, W, qw, nw, amax, 2048);
  gemm_i8_kernel<<<(M / BM) * (Nv / BN), 256, 0, stream>>>(qx, qw, b, amax, out, M, Nv, K);
}